// Round 1
// baseline (2383.839 us; speedup 1.0000x reference)
//
#include <hip/hip_runtime.h>
#include <math.h>

#define T_STEPS 2000
#define BATCH   256
#define F_IN    80
#define HDIM    64

__device__ __forceinline__ float sigm_f(float v) {
    v = fminf(fmaxf(v, -30.f), 30.f);
    return 1.f / (1.f + __expf(-v));
}
__device__ __forceinline__ float tanh_f(float v) {
    v = fminf(fmaxf(v, -15.f), 15.f);
    float e = __expf(-2.f * v);
    return (1.f - e) / (1.f + e);
}

// One block per batch row. 384 threads:
//   tid   0..191 : layer-0 gate engines (gate g = tid), dot K = 80(x) + 64(h0)
//   tid 192..383 : layer-1 gate engines (gate g = tid-192), dot K = 64(h0) + 64(h1)
// Layer-1 at iteration t processes step t-1 (software pipeline) -> 2 barriers/step.
__global__ __launch_bounds__(384, 1)
void gru_fused_kernel(const float* __restrict__ x,      // [B,T,F]
                      const float* __restrict__ hin,    // [2,B,H]
                      const float* __restrict__ Wih0,   // [192,80]
                      const float* __restrict__ Whh0,   // [192,64]
                      const float* __restrict__ bih0, const float* __restrict__ bhh0,
                      const float* __restrict__ Wih1,   // [192,64]
                      const float* __restrict__ Whh1,   // [192,64]
                      const float* __restrict__ bih1, const float* __restrict__ bhh1,
                      float* __restrict__ out_hidden)   // [2,B,H] region of d_out
{
    const int b   = blockIdx.x;
    const int tid = threadIdx.x;

    __shared__ __align__(16) float xh[F_IN + HDIM];   // [x_t (80) | h0 (64)]
    __shared__ __align__(16) float v1[2 * HDIM];      // [h0_new (64) | h1 (64)]
    __shared__ __align__(16) float pre0[2 * HDIM];    // L0 r,z pre-activations
    __shared__ __align__(16) float nx0[HDIM], nh0[HDIM];
    __shared__ __align__(16) float pre1[2 * HDIM];    // L1 r,z pre-activations
    __shared__ __align__(16) float nx1[HDIM], nh1[HDIM];

    // ---- load this thread's weight rows into registers ----
    float4 wa[20];   // L0: W_ih row (80) ; L1: W_ih1 row (64, uses [0..16))
    float4 wb[16];   // L0: W_hh0 row (64); L1: W_hh1 row (64)
    float bi = 0.f, bh = 0.f;
    if (tid < 192) {
        const int g = tid;
        const float4* wi = (const float4*)(Wih0 + g * F_IN);
        #pragma unroll
        for (int q = 0; q < 20; ++q) wa[q] = wi[q];
        const float4* wh = (const float4*)(Whh0 + g * HDIM);
        #pragma unroll
        for (int q = 0; q < 16; ++q) wb[q] = wh[q];
        bi = bih0[g]; bh = bhh0[g];
    } else {
        const int g = tid - 192;
        const float4* wi = (const float4*)(Wih1 + g * HDIM);
        #pragma unroll
        for (int q = 0; q < 16; ++q) wa[q] = wi[q];
        const float4* wh = (const float4*)(Whh1 + g * HDIM);
        #pragma unroll
        for (int q = 0; q < 16; ++q) wb[q] = wh[q];
        bi = bih1[g]; bh = bhh1[g];
    }

    // ---- init LDS: h0, h1, x_0 ----
    if (tid < HDIM) {
        xh[F_IN + tid] = hin[b * HDIM + tid];                    // h0 init
        v1[HDIM + tid] = hin[BATCH * HDIM + b * HDIM + tid];     // h1 init
    }
    if (tid >= 128 && tid < 148) {                               // stage x_0
        int q = tid - 128;
        ((float4*)xh)[q] = ((const float4*)(x + (size_t)b * T_STEPS * F_IN))[q];
    }
    __syncthreads();

    const float4* X4 = (const float4*)xh;
    const float4* V4 = (const float4*)v1;

    for (int t = 0; t <= T_STEPS; ++t) {
        // ======== phase 1: matvec dots ========
        if (tid < 192) {
            if (t < T_STEPS) {
                const int g = tid;
                float a0 = 0.f, a1 = 0.f, a2 = 0.f, a3 = 0.f;
                #pragma unroll
                for (int q = 0; q < 20; ++q) {
                    float4 w = wa[q]; float4 v = X4[q];
                    a0 += w.x * v.x; a1 += w.y * v.y; a2 += w.z * v.z; a3 += w.w * v.w;
                }
                float accx = (a0 + a1) + (a2 + a3);
                float c0 = 0.f, c1 = 0.f, c2 = 0.f, c3 = 0.f;
                #pragma unroll
                for (int q = 0; q < 16; ++q) {
                    float4 w = wb[q]; float4 v = X4[20 + q];
                    c0 += w.x * v.x; c1 += w.y * v.y; c2 += w.z * v.z; c3 += w.w * v.w;
                }
                float acch = (c0 + c1) + (c2 + c3);
                if (g < 128) pre0[g] = accx + acch + bi + bh;
                else { nx0[g - 128] = accx + bi; nh0[g - 128] = acch + bh; }
            }
        } else {
            if (t > 0) {
                const int g = tid - 192;
                float a0 = 0.f, a1 = 0.f, a2 = 0.f, a3 = 0.f;
                #pragma unroll
                for (int q = 0; q < 16; ++q) {
                    float4 w = wa[q]; float4 v = V4[q];          // h0[t-1]
                    a0 += w.x * v.x; a1 += w.y * v.y; a2 += w.z * v.z; a3 += w.w * v.w;
                }
                float acci = (a0 + a1) + (a2 + a3);
                float c0 = 0.f, c1 = 0.f, c2 = 0.f, c3 = 0.f;
                #pragma unroll
                for (int q = 0; q < 16; ++q) {
                    float4 w = wb[q]; float4 v = V4[16 + q];     // h1[t-2]
                    c0 += w.x * v.x; c1 += w.y * v.y; c2 += w.z * v.z; c3 += w.w * v.w;
                }
                float acch = (c0 + c1) + (c2 + c3);
                if (g < 128) pre1[g] = acci + acch + bi + bh;
                else { nx1[g - 128] = acci + bi; nh1[g - 128] = acch + bh; }
            }
        }
        __syncthreads();

        // ======== phase 2: elementwise updates + x staging ========
        if (tid < 64) {
            if (t < T_STEPS) {                 // layer-0 update for step t
                const int j = tid;
                float r = sigm_f(pre0[j]);
                float z = sigm_f(pre0[64 + j]);
                float n = tanh_f(nx0[j] + r * nh0[j]);
                float hp = xh[F_IN + j];
                float hn = (1.f - z) * n + z * hp;
                xh[F_IN + j] = hn;             // feeds L0 step t+1
                v1[j] = hn;                    // feeds L1 step t (next iter)
            }
        } else if (tid < 128) {
            if (t > 0) {                       // layer-1 update for step t-1
                const int j = tid - 64;
                float r = sigm_f(pre1[j]);
                float z = sigm_f(pre1[64 + j]);
                float n = tanh_f(nx1[j] + r * nh1[j]);
                float hp = v1[HDIM + j];
                float hn = (1.f - z) * n + z * hp;
                v1[HDIM + j] = hn;
            }
        } else if (tid < 148) {
            if (t + 1 < T_STEPS) {             // stage x_{t+1}
                int q = tid - 128;
                ((float4*)xh)[q] =
                    ((const float4*)(x + (size_t)b * T_STEPS * F_IN + (size_t)(t + 1) * F_IN))[q];
            }
        }
        __syncthreads();
    }

    // ---- final hidden states: hidden[0]=h0T, hidden[1]=h1T ----
    if (tid < HDIM) {
        out_hidden[b * HDIM + tid]               = xh[F_IN + tid];
        out_hidden[BATCH * HDIM + b * HDIM + tid] = v1[HDIM + tid];
    }
}

// logits[b][o] = b_fc[o] + sum_j relu(h1T[b][j]) * W_fc[o][j]
__global__ void fc_kernel(const float* __restrict__ hidden,   // [2,B,H] region
                          const float* __restrict__ Wfc,      // [29,64]
                          const float* __restrict__ bfc,      // [29]
                          float* __restrict__ logits)         // [B,29]
{
    const int b = blockIdx.x;
    const int o = threadIdx.x;
    if (o < 29) {
        const float* hb = hidden + BATCH * HDIM + b * HDIM;   // h1T
        float acc = bfc[o];
        #pragma unroll
        for (int j = 0; j < HDIM; ++j)
            acc += fmaxf(hb[j], 0.f) * Wfc[o * HDIM + j];
        logits[b * 29 + o] = acc;
    }
}

extern "C" void kernel_launch(void* const* d_in, const int* in_sizes, int n_in,
                              void* d_out, int out_size, void* d_ws, size_t ws_size,
                              hipStream_t stream) {
    const float* x    = (const float*)d_in[0];
    const float* h    = (const float*)d_in[1];
    const float* Wih0 = (const float*)d_in[2];
    const float* Whh0 = (const float*)d_in[3];
    const float* bih0 = (const float*)d_in[4];
    const float* bhh0 = (const float*)d_in[5];
    const float* Wih1 = (const float*)d_in[6];
    const float* Whh1 = (const float*)d_in[7];
    const float* bih1 = (const float*)d_in[8];
    const float* bhh1 = (const float*)d_in[9];
    const float* Wfc  = (const float*)d_in[10];
    const float* bfc  = (const float*)d_in[11];

    float* out = (float*)d_out;
    float* logits = out;                      // [256,29] = 7424
    float* hidden = out + BATCH * 29;         // [2,256,64] = 32768

    gru_fused_kernel<<<BATCH, 384, 0, stream>>>(
        x, h, Wih0, Whh0, bih0, bhh0, Wih1, Whh1, bih1, bhh1, hidden);

    fc_kernel<<<BATCH, 64, 0, stream>>>(hidden, Wfc, bfc, logits);
}

// Round 2
// 2260.940 us; speedup vs baseline: 1.0544x; 1.0544x over previous
//
#include <hip/hip_runtime.h>
#include <math.h>

#define T_STEPS 2000
#define BATCH   256
#define F_IN    80
#define HDIM    64

// ---- fast transcendentals (fp32, ~1ulp rcp; threshold is 1.77e-2) ----
__device__ __forceinline__ float sigm_f(float v) {
    float e = __expf(-v);                       // v->-inf: e=inf, rcp=0 OK
    return __builtin_amdgcn_rcpf(1.f + e);
}
__device__ __forceinline__ float tanh_f(float v) {
    v = fminf(fmaxf(v, -15.f), 15.f);           // keep exp finite
    float e = __expf(-2.f * v);
    return (1.f - e) * __builtin_amdgcn_rcpf(1.f + e);
}
// quad (lanes ks=0..3) sum via DPP quad_perm: xor1 then xor2 — VALU only, no DS.
__device__ __forceinline__ float qred(float v) {
    v += __int_as_float(__builtin_amdgcn_mov_dpp(__float_as_int(v), 0xB1, 0xF, 0xF, true));
    v += __int_as_float(__builtin_amdgcn_mov_dpp(__float_as_int(v), 0x4E, 0xF, 0xF, true));
    return v;
}
__device__ __forceinline__ float sel4(float s0, float s1, float s2, float s3, int ks) {
    float a = (ks & 1) ? s1 : s0;
    float b = (ks & 1) ? s3 : s2;
    return (ks & 2) ? b : a;
}

// One block per batch row. 384 threads = 6 waves.
//   wave 0/1/2 : layer-0 r/z/n gate engines (64 gates each)
//   wave 3/4/5 : layer-1 r/z/n (pipelined one step behind)
// Per thread: G=4 gates x S=1/4 of K. ks=lane&3 picks K-chunk, gg=lane>>2 picks
// gate group. Quad DPP reduction; writer lane's gate == lane (gg*4+ks == lane).
// ONE barrier per step: every wave redundantly computes the h-updates it needs
// from last iter's gate-sums, writes h to LDS itself, reads back own writes
// (cross-wave same-addr writes carry identical values -> benign).
__global__ __launch_bounds__(384, 2)
void gru_fused(const float* __restrict__ x,      // [B,T,F]
               const float* __restrict__ hin,    // [2,B,H]
               const float* __restrict__ Wih0,   // [192,80]
               const float* __restrict__ Whh0,   // [192,64]
               const float* __restrict__ bih0, const float* __restrict__ bhh0,
               const float* __restrict__ Wih1,   // [192,64]
               const float* __restrict__ Whh1,   // [192,64]
               const float* __restrict__ bih1, const float* __restrict__ bhh1,
               float* __restrict__ out_hidden)   // [2,B,H] region of d_out
{
    const int b    = blockIdx.x;
    const int tid  = threadIdx.x;
    const int lane = tid & 63;
    const int w    = tid >> 6;                 // 0..5
    const bool isL1 = (w >= 3);
    const int role = isL1 ? (w - 3) : w;       // 0=r,1=z,2=n
    const int ks   = lane & 3;
    const int gg   = lane >> 2;

    __shared__ __align__(16) float xs[3][F_IN];       // x triple buffer
    __shared__ __align__(16) float h0s[2][HDIM];      // h0 ping-pong (by step parity)
    __shared__ __align__(16) float h1s[2][HDIM];
    __shared__ __align__(16) float gs0[2][4 * HDIM];  // [r|z|nx|nh] ping-pong
    __shared__ __align__(16) float gs1[2][4 * HDIM];

    // ---- weights into registers (transposed per-thread blocks) ----
    // L0: wxr[i][0..19] over x-chunk ks*20.., whr[i][0..15] over h-chunk ks*16..
    // L1: wxr[i][0..15] over h0-chunk,        whr[i][0..15] over h1-chunk
    float wxr[4][20];
    float whr[4][16];
    const int gbase = role * 64;
    if (!isL1) {
        #pragma unroll
        for (int i = 0; i < 4; ++i) {
            const int g = gbase + gg * 4 + i;
            const float* wi = Wih0 + g * F_IN + ks * 20;
            #pragma unroll
            for (int j = 0; j < 20; ++j) wxr[i][j] = wi[j];
            const float* wh = Whh0 + g * HDIM + ks * 16;
            #pragma unroll
            for (int j = 0; j < 16; ++j) whr[i][j] = wh[j];
        }
    } else {
        #pragma unroll
        for (int i = 0; i < 4; ++i) {
            const int g = gbase + gg * 4 + i;
            const float* wi = Wih1 + g * HDIM + ks * 16;
            #pragma unroll
            for (int j = 0; j < 16; ++j) wxr[i][j] = wi[j];
            const float* wh = Whh1 + g * HDIM + ks * 16;
            #pragma unroll
            for (int j = 0; j < 16; ++j) whr[i][j] = wh[j];
        }
    }

    // per-lane bias for the gate this lane writes (gate == gbase + lane)
    float bsum = 0.f, bx = 0.f, bh2 = 0.f;
    {
        const int gwr = gbase + lane;
        if (!isL1) {
            if (role < 2) bsum = bih0[gwr] + bhh0[gwr];
            else { bx = bih0[gwr]; bh2 = bhh0[gwr]; }
        } else {
            if (role < 2) bsum = bih1[gwr] + bhh1[gwr];
            else { bx = bih1[gwr]; bh2 = bhh1[gwr]; }
        }
    }

    // ---- state init ----
    float h0reg = hin[b * HDIM + lane];                    // lane j owns h0[j]
    float h1reg = hin[BATCH * HDIM + b * HDIM + lane];
    if (w == 0) {
        h0s[1][lane] = h0reg;    // h0[-1] lives in parity buffer 1
        h1s[1][lane] = h1reg;    // h1[-1]
    }
    const float* xrow = x + (size_t)b * T_STEPS * F_IN;
    float2 xa = make_float2(0.f, 0.f), xb = make_float2(0.f, 0.f);
    if (w == 1 && lane < 40) {   // 40 lanes x float2 = 80 floats
        ((float2*)xs[0])[lane] = ((const float2*)(xrow + 0 * F_IN))[lane];
        ((float2*)xs[1])[lane] = ((const float2*)(xrow + 1 * F_IN))[lane];
        xa = ((const float2*)(xrow + 2 * F_IN))[lane];   // staged for iter 0 write
        xb = ((const float2*)(xrow + 3 * F_IN))[lane];   // staged for iter 1 write
    }
    __syncthreads();

    int slotR = 0, slotW = 2;    // slotR = i%3, slotW = (i+2)%3
    for (int i = 0; i <= T_STEPS + 1; ++i) {
        const int pA0 = (i - 1) & 1;

        // ======== Phase A: updates from last iter's gate-sums ========
        if (i >= 1 && i <= T_STEPS) {            // h0[i-1] (ALL waves, redundant)
            float rv  = gs0[pA0][lane];
            float zv  = gs0[pA0][64 + lane];
            float nxv = gs0[pA0][128 + lane];
            float nhv = gs0[pA0][192 + lane];
            float r = sigm_f(rv);
            float z = sigm_f(zv);
            float n = tanh_f(nxv + r * nhv);
            h0reg = (1.f - z) * n + z * h0reg;
            h0s[pA0][lane] = h0reg;              // parity (i-1)&1
        }
        if (isL1 && i >= 2) {                    // h1[i-2] (L1 waves only)
            const int pA1 = (i - 2) & 1;
            float rv  = gs1[pA1][lane];
            float zv  = gs1[pA1][64 + lane];
            float nxv = gs1[pA1][128 + lane];
            float nhv = gs1[pA1][192 + lane];
            float r = sigm_f(rv);
            float z = sigm_f(zv);
            float n = tanh_f(nxv + r * nhv);
            h1reg = (1.f - z) * n + z * h1reg;
            h1s[pA1][lane] = h1reg;
        }

        // ======== x staging (wave 1): reg->LDS at dist 2, load at dist 4 ========
        if (w == 1 && lane < 40) {
            if (i + 2 <= T_STEPS - 1)
                ((float2*)xs[slotW])[lane] = (i & 1) ? xb : xa;
            if (i + 4 <= T_STEPS - 1) {
                const float2* src = (const float2*)(xrow + (size_t)(i + 4) * F_IN);
                float2 v = src[lane];
                if (i & 1) xb = v; else xa = v;
            }
        }

        // ======== Phase B: matvec for this iter's step ========
        if (!isL1) {
            if (i < T_STEPS) {                   // L0 step t=i: x[i], h0[i-1]
                const float4* xp = (const float4*)(xs[slotR] + ks * 20);
                const float4* hp = (const float4*)(h0s[pA0] + ks * 16);
                float ax0=0.f,ax1=0.f,ax2=0.f,ax3=0.f;
                float ah0=0.f,ah1=0.f,ah2=0.f,ah3=0.f;
                #pragma unroll
                for (int q = 0; q < 5; ++q) {
                    float4 a = xp[q];
                    ax0=fmaf(wxr[0][4*q+0],a.x,ax0); ax0=fmaf(wxr[0][4*q+1],a.y,ax0);
                    ax0=fmaf(wxr[0][4*q+2],a.z,ax0); ax0=fmaf(wxr[0][4*q+3],a.w,ax0);
                    ax1=fmaf(wxr[1][4*q+0],a.x,ax1); ax1=fmaf(wxr[1][4*q+1],a.y,ax1);
                    ax1=fmaf(wxr[1][4*q+2],a.z,ax1); ax1=fmaf(wxr[1][4*q+3],a.w,ax1);
                    ax2=fmaf(wxr[2][4*q+0],a.x,ax2); ax2=fmaf(wxr[2][4*q+1],a.y,ax2);
                    ax2=fmaf(wxr[2][4*q+2],a.z,ax2); ax2=fmaf(wxr[2][4*q+3],a.w,ax2);
                    ax3=fmaf(wxr[3][4*q+0],a.x,ax3); ax3=fmaf(wxr[3][4*q+1],a.y,ax3);
                    ax3=fmaf(wxr[3][4*q+2],a.z,ax3); ax3=fmaf(wxr[3][4*q+3],a.w,ax3);
                }
                #pragma unroll
                for (int q = 0; q < 4; ++q) {
                    float4 a = hp[q];
                    ah0=fmaf(whr[0][4*q+0],a.x,ah0); ah0=fmaf(whr[0][4*q+1],a.y,ah0);
                    ah0=fmaf(whr[0][4*q+2],a.z,ah0); ah0=fmaf(whr[0][4*q+3],a.w,ah0);
                    ah1=fmaf(whr[1][4*q+0],a.x,ah1); ah1=fmaf(whr[1][4*q+1],a.y,ah1);
                    ah1=fmaf(whr[1][4*q+2],a.z,ah1); ah1=fmaf(whr[1][4*q+3],a.w,ah1);
                    ah2=fmaf(whr[2][4*q+0],a.x,ah2); ah2=fmaf(whr[2][4*q+1],a.y,ah2);
                    ah2=fmaf(whr[2][4*q+2],a.z,ah2); ah2=fmaf(whr[2][4*q+3],a.w,ah2);
                    ah3=fmaf(whr[3][4*q+0],a.x,ah3); ah3=fmaf(whr[3][4*q+1],a.y,ah3);
                    ah3=fmaf(whr[3][4*q+2],a.z,ah3); ah3=fmaf(whr[3][4*q+3],a.w,ah3);
                }
                const int pB = i & 1;
                if (role < 2) {
                    float s0=qred(ax0+ah0), s1=qred(ax1+ah1), s2=qred(ax2+ah2), s3=qred(ax3+ah3);
                    gs0[pB][role * 64 + lane] = sel4(s0,s1,s2,s3,ks) + bsum;
                } else {
                    float sx = sel4(qred(ax0),qred(ax1),qred(ax2),qred(ax3),ks);
                    float sh = sel4(qred(ah0),qred(ah1),qred(ah2),qred(ah3),ks);
                    gs0[pB][128 + lane] = sx + bx;
                    gs0[pB][192 + lane] = sh + bh2;
                }
            }
        } else {
            if (i >= 1 && i <= T_STEPS) {        // L1 step t=i-1: h0[i-1], h1[i-2]
                const float4* xp = (const float4*)(h0s[pA0] + ks * 16);
                const float4* hp = (const float4*)(h1s[(i - 2) & 1] + ks * 16);
                float ax0=0.f,ax1=0.f,ax2=0.f,ax3=0.f;
                float ah0=0.f,ah1=0.f,ah2=0.f,ah3=0.f;
                #pragma unroll
                for (int q = 0; q < 4; ++q) {
                    float4 a = xp[q];
                    ax0=fmaf(wxr[0][4*q+0],a.x,ax0); ax0=fmaf(wxr[0][4*q+1],a.y,ax0);
                    ax0=fmaf(wxr[0][4*q+2],a.z,ax0); ax0=fmaf(wxr[0][4*q+3],a.w,ax0);
                    ax1=fmaf(wxr[1][4*q+0],a.x,ax1); ax1=fmaf(wxr[1][4*q+1],a.y,ax1);
                    ax1=fmaf(wxr[1][4*q+2],a.z,ax1); ax1=fmaf(wxr[1][4*q+3],a.w,ax1);
                    ax2=fmaf(wxr[2][4*q+0],a.x,ax2); ax2=fmaf(wxr[2][4*q+1],a.y,ax2);
                    ax2=fmaf(wxr[2][4*q+2],a.z,ax2); ax2=fmaf(wxr[2][4*q+3],a.w,ax2);
                    ax3=fmaf(wxr[3][4*q+0],a.x,ax3); ax3=fmaf(wxr[3][4*q+1],a.y,ax3);
                    ax3=fmaf(wxr[3][4*q+2],a.z,ax3); ax3=fmaf(wxr[3][4*q+3],a.w,ax3);
                }
                #pragma unroll
                for (int q = 0; q < 4; ++q) {
                    float4 a = hp[q];
                    ah0=fmaf(whr[0][4*q+0],a.x,ah0); ah0=fmaf(whr[0][4*q+1],a.y,ah0);
                    ah0=fmaf(whr[0][4*q+2],a.z,ah0); ah0=fmaf(whr[0][4*q+3],a.w,ah0);
                    ah1=fmaf(whr[1][4*q+0],a.x,ah1); ah1=fmaf(whr[1][4*q+1],a.y,ah1);
                    ah1=fmaf(whr[1][4*q+2],a.z,ah1); ah1=fmaf(whr[1][4*q+3],a.w,ah1);
                    ah2=fmaf(whr[2][4*q+0],a.x,ah2); ah2=fmaf(whr[2][4*q+1],a.y,ah2);
                    ah2=fmaf(whr[2][4*q+2],a.z,ah2); ah2=fmaf(whr[2][4*q+3],a.w,ah2);
                    ah3=fmaf(whr[3][4*q+0],a.x,ah3); ah3=fmaf(whr[3][4*q+1],a.y,ah3);
                    ah3=fmaf(whr[3][4*q+2],a.z,ah3); ah3=fmaf(whr[3][4*q+3],a.w,ah3);
                }
                const int pB = (i - 1) & 1;
                if (role < 2) {
                    float s0=qred(ax0+ah0), s1=qred(ax1+ah1), s2=qred(ax2+ah2), s3=qred(ax3+ah3);
                    gs1[pB][role * 64 + lane] = sel4(s0,s1,s2,s3,ks) + bsum;
                } else {
                    float sx = sel4(qred(ax0),qred(ax1),qred(ax2),qred(ax3),ks);
                    float sh = sel4(qred(ah0),qred(ah1),qred(ah2),qred(ah3),ks);
                    gs1[pB][128 + lane] = sx + bx;
                    gs1[pB][192 + lane] = sh + bh2;
                }
            }
        }

        slotR = (slotR == 2) ? 0 : slotR + 1;
        slotW = (slotW == 2) ? 0 : slotW + 1;
        __syncthreads();
    }

    // hidden[0]=h0[T-1] (updated at iter T), hidden[1]=h1[T-1] (iter T+1)
    if (w == 0) out_hidden[b * HDIM + lane] = h0reg;
    if (w == 3) out_hidden[BATCH * HDIM + b * HDIM + lane] = h1reg;
}

// logits[b][o] = b_fc[o] + sum_j relu(h1T[b][j]) * W_fc[o][j]
__global__ void fc_kernel(const float* __restrict__ hidden,   // [2,B,H] region
                          const float* __restrict__ Wfc,      // [29,64]
                          const float* __restrict__ bfc,      // [29]
                          float* __restrict__ logits)         // [B,29]
{
    const int b = blockIdx.x;
    const int o = threadIdx.x;
    if (o < 29) {
        const float* hb = hidden + BATCH * HDIM + b * HDIM;   // h1T
        float acc = bfc[o];
        #pragma unroll
        for (int j = 0; j < HDIM; ++j)
            acc += fmaxf(hb[j], 0.f) * Wfc[o * HDIM + j];
        logits[b * 29 + o] = acc;
    }
}

extern "C" void kernel_launch(void* const* d_in, const int* in_sizes, int n_in,
                              void* d_out, int out_size, void* d_ws, size_t ws_size,
                              hipStream_t stream) {
    const float* x    = (const float*)d_in[0];
    const float* h    = (const float*)d_in[1];
    const float* Wih0 = (const float*)d_in[2];
    const float* Whh0 = (const float*)d_in[3];
    const float* bih0 = (const float*)d_in[4];
    const float* bhh0 = (const float*)d_in[5];
    const float* Wih1 = (const float*)d_in[6];
    const float* Whh1 = (const float*)d_in[7];
    const float* bih1 = (const float*)d_in[8];
    const float* bhh1 = (const float*)d_in[9];
    const float* Wfc  = (const float*)d_in[10];
    const float* bfc  = (const float*)d_in[11];

    float* out    = (float*)d_out;
    float* logits = out;                      // [256,29]
    float* hidden = out + BATCH * 29;         // [2,256,64]

    gru_fused<<<BATCH, 384, 0, stream>>>(
        x, h, Wih0, Whh0, bih0, bhh0, Wih1, Whh1, bih1, bhh1, hidden);

    fc_kernel<<<BATCH, 64, 0, stream>>>(hidden, Wfc, bfc, logits);
}

// Round 3
// 1965.373 us; speedup vs baseline: 1.2129x; 1.1504x over previous
//
#include <hip/hip_runtime.h>
#include <math.h>

#define T_STEPS 2000
#define BATCH   256
#define F_IN    80
#define HDIM    64

// ---- fast transcendentals (fp32; abs threshold is 1.77e-2, plenty of room) ----
__device__ __forceinline__ float sigm_f(float v) {
    float e = __expf(-v);                       // v->-inf: e=inf, rcp->0, OK
    return __builtin_amdgcn_rcpf(1.f + e);
}
__device__ __forceinline__ float tanh_f(float v) {
    v = fminf(fmaxf(v, -15.f), 15.f);
    float e = __expf(-2.f * v);
    return (1.f - e) * __builtin_amdgcn_rcpf(1.f + e);
}
// quad butterfly sum (lanes ks=0..3) via DPP quad_perm — VALU only, all 4 lanes
// end with the full sum.
__device__ __forceinline__ float qred(float v) {
    v += __int_as_float(__builtin_amdgcn_mov_dpp(__float_as_int(v), 0xB1, 0xF, 0xF, true));
    v += __int_as_float(__builtin_amdgcn_mov_dpp(__float_as_int(v), 0x4E, 0xF, 0xF, true));
    return v;
}

// One block per batch row. 512 threads = 8 waves, 2 per SIMD (balanced).
//   waves 0..3 : layer 0.  lane owns unit j = 16*(w&3) + (lane>>2), K-chunk ks=lane&3.
//   waves 4..7 : layer 1, one step behind.
// Each lane accumulates r/z/nx/nh partials for its j over its K-chunk, quad-DPP
// reduces, then does the ENTIRE gate + h update in registers (h_prev[j] is the
// lane's own register). Only LDS on the serial path: h broadcast (write 16
// lanes, read chunked next iter). ONE barrier per iteration.
__global__ __launch_bounds__(512, 2)
void gru_fused(const float* __restrict__ x,      // [B,T,F]
               const float* __restrict__ hin,    // [2,B,H]
               const float* __restrict__ Wih0,   // [192,80]
               const float* __restrict__ Whh0,   // [192,64]
               const float* __restrict__ bih0, const float* __restrict__ bhh0,
               const float* __restrict__ Wih1,   // [192,64]
               const float* __restrict__ Whh1,   // [192,64]
               const float* __restrict__ bih1, const float* __restrict__ bhh1,
               float* __restrict__ out_hidden)   // [2,B,H] region of d_out
{
    const int b    = blockIdx.x;
    const int tid  = threadIdx.x;
    const int lane = tid & 63;
    const int w    = tid >> 6;                  // 0..7
    const bool isL1 = (w >= 4);
    const int ks   = lane & 3;
    const int jw   = ((w & 3) << 4) + (lane >> 2);   // 0..63

    __shared__ __align__(16) float xs[3][F_IN];      // x triple buffer
    __shared__ __align__(16) float h0s[2][HDIM];     // ping-pong by step parity
    __shared__ __align__(16) float h1s[2][HDIM];

    // ---- weights into registers ----
    float wxr[20], wxz[20], wxn[20];   // L0: x-chunk (20). L1: h0-chunk (16)
    float whr[16], whz[16], whn[16];   // L0: h0-chunk.     L1: h1-chunk
    float br, bz, bnx, bnh;
    if (!isL1) {
        const int c = ks * 20, c2 = ks * 16;
        #pragma unroll
        for (int k = 0; k < 20; ++k) {
            wxr[k] = Wih0[jw * F_IN + c + k];
            wxz[k] = Wih0[(64 + jw) * F_IN + c + k];
            wxn[k] = Wih0[(128 + jw) * F_IN + c + k];
        }
        #pragma unroll
        for (int k = 0; k < 16; ++k) {
            whr[k] = Whh0[jw * HDIM + c2 + k];
            whz[k] = Whh0[(64 + jw) * HDIM + c2 + k];
            whn[k] = Whh0[(128 + jw) * HDIM + c2 + k];
        }
        br  = bih0[jw] + bhh0[jw];
        bz  = bih0[64 + jw] + bhh0[64 + jw];
        bnx = bih0[128 + jw];
        bnh = bhh0[128 + jw];
    } else {
        const int c2 = ks * 16;
        #pragma unroll
        for (int k = 0; k < 16; ++k) {
            wxr[k] = Wih1[jw * HDIM + c2 + k];
            wxz[k] = Wih1[(64 + jw) * HDIM + c2 + k];
            wxn[k] = Wih1[(128 + jw) * HDIM + c2 + k];
            whr[k] = Whh1[jw * HDIM + c2 + k];
            whz[k] = Whh1[(64 + jw) * HDIM + c2 + k];
            whn[k] = Whh1[(128 + jw) * HDIM + c2 + k];
        }
        #pragma unroll
        for (int k = 16; k < 20; ++k) { wxr[k] = 0.f; wxz[k] = 0.f; wxn[k] = 0.f; }
        br  = bih1[jw] + bhh1[jw];
        bz  = bih1[64 + jw] + bhh1[64 + jw];
        bnx = bih1[128 + jw];
        bnh = bhh1[128 + jw];
    }

    // ---- state init ----
    float hreg = isL1 ? hin[BATCH * HDIM + b * HDIM + jw]   // lane's own h[j]
                      : hin[b * HDIM + jw];
    if (w == 0) {
        h0s[1][lane] = hin[b * HDIM + lane];                 // h0[-1] (read at i=0)
        h1s[1][lane] = hin[BATCH * HDIM + b * HDIM + lane];  // h1[-1] (read at i=1)
    }
    const float* xrow = x + (size_t)b * T_STEPS * F_IN;
    float2 xa = make_float2(0.f, 0.f), xb = make_float2(0.f, 0.f);
    if (w == 7 && lane < 40) {               // 40 lanes x float2 = 80 floats
        ((float2*)xs[0])[lane] = ((const float2*)(xrow + 0 * F_IN))[lane];
        ((float2*)xs[1])[lane] = ((const float2*)(xrow + 1 * F_IN))[lane];
        xa = ((const float2*)(xrow + 2 * F_IN))[lane];
        xb = ((const float2*)(xrow + 3 * F_IN))[lane];
    }
    __syncthreads();

    int slotR = 0, slotW = 2;                // i%3 / (i+2)%3
    for (int i = 0; i <= T_STEPS; ++i) {
        // ---- x staging (wave 7): LDS write at dist 2, global load at dist 4 ----
        if (w == 7 && lane < 40) {
            if (i + 2 <= T_STEPS - 1)
                ((float2*)xs[slotW])[lane] = (i & 1) ? xb : xa;
            if (i + 4 <= T_STEPS - 1) {
                float2 v = ((const float2*)(xrow + (size_t)(i + 4) * F_IN))[lane];
                if (i & 1) xb = v; else xa = v;
            }
        }

        if (!isL1) {
            if (i < T_STEPS) {               // L0 step t=i: inputs x[i], h0[i-1]
                const float4* xp = (const float4*)(xs[slotR] + ks * 20);
                const float4* hp = (const float4*)(h0s[(i - 1) & 1] + ks * 16);
                float ar = 0.f, az = 0.f, anx = 0.f, anh = 0.f;
                #pragma unroll
                for (int q = 0; q < 5; ++q) {
                    float4 a = xp[q];
                    const float* e = (const float*)&a;
                    #pragma unroll
                    for (int u = 0; u < 4; ++u) {
                        const int k = 4 * q + u;
                        ar  = fmaf(wxr[k], e[u], ar);
                        az  = fmaf(wxz[k], e[u], az);
                        anx = fmaf(wxn[k], e[u], anx);
                    }
                }
                #pragma unroll
                for (int q = 0; q < 4; ++q) {
                    float4 a = hp[q];
                    const float* e = (const float*)&a;
                    #pragma unroll
                    for (int u = 0; u < 4; ++u) {
                        const int k = 4 * q + u;
                        ar  = fmaf(whr[k], e[u], ar);
                        az  = fmaf(whz[k], e[u], az);
                        anh = fmaf(whn[k], e[u], anh);
                    }
                }
                ar  = qred(ar) + br;
                az  = qred(az) + bz;
                anx = qred(anx) + bnx;
                anh = qred(anh) + bnh;
                float r = sigm_f(ar);
                float z = sigm_f(az);
                float n = tanh_f(anx + r * anh);
                hreg = (1.f - z) * n + z * hreg;
                if (ks == 0) h0s[i & 1][jw] = hreg;
            }
        } else {
            if (i >= 1) {                    // L1 step t=i-1: inputs h0[i-1], h1[i-2]
                const float4* xp = (const float4*)(h0s[(i - 1) & 1] + ks * 16);
                const float4* hp = (const float4*)(h1s[i & 1] + ks * 16);
                float ar = 0.f, az = 0.f, anx = 0.f, anh = 0.f;
                #pragma unroll
                for (int q = 0; q < 4; ++q) {
                    float4 a = xp[q];
                    const float* e = (const float*)&a;
                    #pragma unroll
                    for (int u = 0; u < 4; ++u) {
                        const int k = 4 * q + u;
                        ar  = fmaf(wxr[k], e[u], ar);
                        az  = fmaf(wxz[k], e[u], az);
                        anx = fmaf(wxn[k], e[u], anx);
                    }
                }
                #pragma unroll
                for (int q = 0; q < 4; ++q) {
                    float4 a = hp[q];
                    const float* e = (const float*)&a;
                    #pragma unroll
                    for (int u = 0; u < 4; ++u) {
                        const int k = 4 * q + u;
                        ar  = fmaf(whr[k], e[u], ar);
                        az  = fmaf(whz[k], e[u], az);
                        anh = fmaf(whn[k], e[u], anh);
                    }
                }
                ar  = qred(ar) + br;
                az  = qred(az) + bz;
                anx = qred(anx) + bnx;
                anh = qred(anh) + bnh;
                float r = sigm_f(ar);
                float z = sigm_f(az);
                float n = tanh_f(anx + r * anh);
                hreg = (1.f - z) * n + z * hreg;
                if (ks == 0) h1s[(i - 1) & 1][jw] = hreg;
            }
        }

        slotR = (slotR == 2) ? 0 : slotR + 1;
        slotW = (slotW == 2) ? 0 : slotW + 1;
        __syncthreads();
    }

    // hreg holds h0[T-1] (L0 lanes) / h1[T-1] (L1 lanes); ks==0 lanes cover all j.
    if (ks == 0) {
        if (!isL1) out_hidden[b * HDIM + jw] = hreg;
        else       out_hidden[BATCH * HDIM + b * HDIM + jw] = hreg;
    }
}

// logits[b][o] = b_fc[o] + sum_j relu(h1T[b][j]) * W_fc[o][j]
__global__ void fc_kernel(const float* __restrict__ hidden,   // [2,B,H] region
                          const float* __restrict__ Wfc,      // [29,64]
                          const float* __restrict__ bfc,      // [29]
                          float* __restrict__ logits)         // [B,29]
{
    const int b = blockIdx.x;
    const int o = threadIdx.x;
    if (o < 29) {
        const float* hb = hidden + BATCH * HDIM + b * HDIM;   // h1T
        float acc = bfc[o];
        #pragma unroll
        for (int j = 0; j < HDIM; ++j)
            acc += fmaxf(hb[j], 0.f) * Wfc[o * HDIM + j];
        logits[b * 29 + o] = acc;
    }
}

extern "C" void kernel_launch(void* const* d_in, const int* in_sizes, int n_in,
                              void* d_out, int out_size, void* d_ws, size_t ws_size,
                              hipStream_t stream) {
    const float* x    = (const float*)d_in[0];
    const float* h    = (const float*)d_in[1];
    const float* Wih0 = (const float*)d_in[2];
    const float* Whh0 = (const float*)d_in[3];
    const float* bih0 = (const float*)d_in[4];
    const float* bhh0 = (const float*)d_in[5];
    const float* Wih1 = (const float*)d_in[6];
    const float* Whh1 = (const float*)d_in[7];
    const float* bih1 = (const float*)d_in[8];
    const float* bhh1 = (const float*)d_in[9];
    const float* Wfc  = (const float*)d_in[10];
    const float* bfc  = (const float*)d_in[11];

    float* out    = (float*)d_out;
    float* logits = out;                      // [256,29]
    float* hidden = out + BATCH * 29;         // [2,256,64]

    gru_fused<<<BATCH, 512, 0, stream>>>(
        x, h, Wih0, Whh0, bih0, bhh0, Wih1, Whh1, bih1, bhh1, hidden);

    fc_kernel<<<BATCH, 64, 0, stream>>>(hidden, Wfc, bfc, logits);
}

// Round 4
// 1521.297 us; speedup vs baseline: 1.5670x; 1.2919x over previous
//
#include <hip/hip_runtime.h>

#define T_STEPS 2000
#define BATCH   256
#define F_IN    80
#define HDIM    64

template<int N> struct IC { static constexpr int v = N; };

// ---- fast transcendentals (fp32; logits threshold 1.77e-2) ----
__device__ __forceinline__ float sigm_f(float v) {
    float e = __expf(-v);                       // v->-inf: e=inf, rcp->0, OK
    return __builtin_amdgcn_rcpf(1.f + e);
}
__device__ __forceinline__ float tanh_f(float v) {
    v = fminf(fmaxf(v, -15.f), 15.f);
    float e = __expf(-2.f * v);
    return (1.f - e) * __builtin_amdgcn_rcpf(1.f + e);
}
// quad butterfly sum (lanes ks=0..3) via DPP quad_perm — VALU only.
__device__ __forceinline__ float qred(float v) {
    v += __int_as_float(__builtin_amdgcn_mov_dpp(__float_as_int(v), 0xB1, 0xF, 0xF, true));
    v += __int_as_float(__builtin_amdgcn_mov_dpp(__float_as_int(v), 0x4E, 0xF, 0xF, true));
    return v;
}
// CK-style LDS-only barrier: waits own LDS ops (lgkmcnt=0) but leaves global
// loads in flight (vmcnt=63) — avoids __syncthreads' vmcnt(0) drain, which
// would force wave 7's x-prefetch (HBM ~900cyc) to complete every iteration.
__device__ __forceinline__ void barrier_lds() {
    __builtin_amdgcn_s_waitcnt(0xC07F);   // vmcnt=63, expcnt=7, lgkmcnt=0
    __builtin_amdgcn_s_barrier();
}

// One block per batch row. 512 threads = 8 waves, 2/SIMD.
//   waves 0..3 : layer 0. lane owns unit jw = 16*(w&3)+(lane>>2); K-chunk ks=lane&3.
//   waves 4..7 : layer 1, one step behind. wave 7 also stages x.
// L0's x-projection gx[i+1] is produced at iter i into REGISTERS (consumer =
// same lane) — off the serial chain. On-chain per step: ds_read h chunks
// (batched, padded 4x20 layout = conflict-free) -> 48 FMA -> qred -> gates ->
// ds_write h. h buffers ping-pong by step parity (compile-time via unroll x2).
__global__ __launch_bounds__(512, 2)
void gru_fused(const float* __restrict__ x,      // [B,T,F]
               const float* __restrict__ hin,    // [2,B,H]
               const float* __restrict__ Wih0,   // [192,80]
               const float* __restrict__ Whh0,   // [192,64]
               const float* __restrict__ bih0, const float* __restrict__ bhh0,
               const float* __restrict__ Wih1,   // [192,64]
               const float* __restrict__ Whh1,   // [192,64]
               const float* __restrict__ bih1, const float* __restrict__ bhh1,
               float* __restrict__ out_hidden)   // [2,B,H] region of d_out
{
    const int b    = blockIdx.x;
    const int tid  = threadIdx.x;
    const int lane = tid & 63;
    const int w    = tid >> 6;                  // 0..7
    const bool isL1 = (w >= 4);
    const int ks   = lane & 3;
    const int gg   = lane >> 2;
    const int jw   = ((w & 3) << 4) + gg;       // unit this lane owns
    const int caddr = (w & 3) * 20 + gg;        // padded write addr for jw

    // padded layouts: 2 slots x 4 chunks x 20 floats (chunk k at k*20, 16 used)
    __shared__ __align__(16) float xsBuf[160];  // x: 2 slots x 80 (chunks of 20, all used)
    __shared__ __align__(16) float h0Buf[160];
    __shared__ __align__(16) float h1Buf[160];

    // ---- weights into registers ----
    float wxr[20], wxz[20], wxn[20];   // L0: x-chunk(20). L1: Wih1 h0-chunk(16)
    float whr[16], whz[16], whn[16];   // L0: Whh0 chunk.  L1: Whh1 h1-chunk
    float bihr, bihz, bihn, bhhr, bhhz, bhhn;
    if (!isL1) {
        const int c = ks * 20, c2 = ks * 16;
        #pragma unroll
        for (int k = 0; k < 20; ++k) {
            wxr[k] = Wih0[jw * F_IN + c + k];
            wxz[k] = Wih0[(64 + jw) * F_IN + c + k];
            wxn[k] = Wih0[(128 + jw) * F_IN + c + k];
        }
        #pragma unroll
        for (int k = 0; k < 16; ++k) {
            whr[k] = Whh0[jw * HDIM + c2 + k];
            whz[k] = Whh0[(64 + jw) * HDIM + c2 + k];
            whn[k] = Whh0[(128 + jw) * HDIM + c2 + k];
        }
        bihr = bih0[jw];       bhhr = bhh0[jw];
        bihz = bih0[64 + jw];  bhhz = bhh0[64 + jw];
        bihn = bih0[128 + jw]; bhhn = bhh0[128 + jw];
    } else {
        const int c2 = ks * 16;
        #pragma unroll
        for (int k = 0; k < 16; ++k) {
            wxr[k] = Wih1[jw * HDIM + c2 + k];
            wxz[k] = Wih1[(64 + jw) * HDIM + c2 + k];
            wxn[k] = Wih1[(128 + jw) * HDIM + c2 + k];
            whr[k] = Whh1[jw * HDIM + c2 + k];
            whz[k] = Whh1[(64 + jw) * HDIM + c2 + k];
            whn[k] = Whh1[(128 + jw) * HDIM + c2 + k];
        }
        #pragma unroll
        for (int k = 16; k < 20; ++k) { wxr[k] = 0.f; wxz[k] = 0.f; wxn[k] = 0.f; }
        bihr = bih1[jw] + bhh1[jw];              // r: merged bias
        bihz = bih1[64 + jw] + bhh1[64 + jw];    // z: merged bias
        bihn = bih1[128 + jw];                   // n: x-side bias
        bhhn = bhh1[128 + jw];                   // n: h-side bias
        bhhr = 0.f; bhhz = 0.f;
    }

    // ---- state init ----
    float hreg = isL1 ? hin[BATCH * HDIM + b * HDIM + jw]
                      : hin[b * HDIM + jw];
    if (w == 0) {                                // padded init of slot 1 (= parity of "i-1" at i=0)
        const int c = lane >> 4, p = lane & 15;
        h0Buf[80 + c * 20 + p] = hin[b * HDIM + lane];
        h1Buf[80 + c * 20 + p] = hin[BATCH * HDIM + b * HDIM + lane];
    }
    const float* xrow = x + (size_t)b * T_STEPS * F_IN;
    float2 xa = make_float2(0.f, 0.f), xb = make_float2(0.f, 0.f);
    if (w == 7 && lane < 40) {                   // stage x0,x1; prefetch x2,x3
        ((float2*)(xsBuf +  0))[lane] = ((const float2*)(xrow + 0 * F_IN))[lane];
        ((float2*)(xsBuf + 80))[lane] = ((const float2*)(xrow + 1 * F_IN))[lane];
        xa = ((const float2*)(xrow + 2 * F_IN))[lane];
        xb = ((const float2*)(xrow + 3 * F_IN))[lane];
    }
    __syncthreads();   // prologue: full sync is fine (once)

    // gx[0] from xs slot 0 (registers; includes bih)
    float gxr = 0.f, gxz = 0.f, gxn = 0.f;
    if (!isL1) {
        const float4* xp = (const float4*)(xsBuf + ks * 20);
        float axr = 0.f, axz = 0.f, axn = 0.f;
        float4 xq[5];
        #pragma unroll
        for (int q = 0; q < 5; ++q) xq[q] = xp[q];
        #pragma unroll
        for (int q = 0; q < 5; ++q) {
            const float4 a = xq[q];
            axr = fmaf(wxr[4*q+0], a.x, axr); axr = fmaf(wxr[4*q+1], a.y, axr);
            axr = fmaf(wxr[4*q+2], a.z, axr); axr = fmaf(wxr[4*q+3], a.w, axr);
            axz = fmaf(wxz[4*q+0], a.x, axz); axz = fmaf(wxz[4*q+1], a.y, axz);
            axz = fmaf(wxz[4*q+2], a.z, axz); axz = fmaf(wxz[4*q+3], a.w, axz);
            axn = fmaf(wxn[4*q+0], a.x, axn); axn = fmaf(wxn[4*q+1], a.y, axn);
            axn = fmaf(wxn[4*q+2], a.z, axn); axn = fmaf(wxn[4*q+3], a.w, axn);
        }
        gxr = qred(axr) + bihr; gxz = qred(axz) + bihz; gxn = qred(axn) + bihn;
    }

    auto step = [&](int i, auto ipc) {
        constexpr int IP = decltype(ipc)::v;   // i&1
        constexpr int IO = IP ^ 1;             // (i-1)&1 == (i+1)&1

        // ---- x staging (wave 7): write x[i+2] -> slot IP; prefetch x[i+4] ----
        if (w == 7 && lane < 40) {
            ((float2*)(xsBuf + IP * 80))[lane] = (IP == 0) ? xa : xb;
            if (i <= T_STEPS - 5) {
                float2 v = ((const float2*)(xrow + (size_t)(i + 4) * F_IN))[lane];
                if (IP == 0) xa = v; else xb = v;
            }
        }

        if (!isL1) {
            // batched reads: h0[i-1] chunks + x[i+1] chunks
            const float4* hp = (const float4*)(h0Buf + IO * 80 + ks * 20);
            const float4* xp = (const float4*)(xsBuf + IO * 80 + ks * 20);
            float4 hq[4], xq[5];
            #pragma unroll
            for (int q = 0; q < 4; ++q) hq[q] = hp[q];
            #pragma unroll
            for (int q = 0; q < 5; ++q) xq[q] = xp[q];

            // on-chain: gh = Whh0 . h0[i-1]
            float ahr = 0.f, ahz = 0.f, ahn = 0.f;
            #pragma unroll
            for (int q = 0; q < 4; ++q) {
                const float4 a = hq[q];
                ahr = fmaf(whr[4*q+0], a.x, ahr); ahr = fmaf(whr[4*q+1], a.y, ahr);
                ahr = fmaf(whr[4*q+2], a.z, ahr); ahr = fmaf(whr[4*q+3], a.w, ahr);
                ahz = fmaf(whz[4*q+0], a.x, ahz); ahz = fmaf(whz[4*q+1], a.y, ahz);
                ahz = fmaf(whz[4*q+2], a.z, ahz); ahz = fmaf(whz[4*q+3], a.w, ahz);
                ahn = fmaf(whn[4*q+0], a.x, ahn); ahn = fmaf(whn[4*q+1], a.y, ahn);
                ahn = fmaf(whn[4*q+2], a.z, ahn); ahn = fmaf(whn[4*q+3], a.w, ahn);
            }
            // off-chain: gx[i+1] = Wih0 . x[i+1]  (indep work; fills stalls)
            float axr = 0.f, axz = 0.f, axn = 0.f;
            #pragma unroll
            for (int q = 0; q < 5; ++q) {
                const float4 a = xq[q];
                axr = fmaf(wxr[4*q+0], a.x, axr); axr = fmaf(wxr[4*q+1], a.y, axr);
                axr = fmaf(wxr[4*q+2], a.z, axr); axr = fmaf(wxr[4*q+3], a.w, axr);
                axz = fmaf(wxz[4*q+0], a.x, axz); axz = fmaf(wxz[4*q+1], a.y, axz);
                axz = fmaf(wxz[4*q+2], a.z, axz); axz = fmaf(wxz[4*q+3], a.w, axz);
                axn = fmaf(wxn[4*q+0], a.x, axn); axn = fmaf(wxn[4*q+1], a.y, axn);
                axn = fmaf(wxn[4*q+2], a.z, axn); axn = fmaf(wxn[4*q+3], a.w, axn);
            }
            // gates + update for step i (consumes gx[i] from registers)
            float r = sigm_f(gxr + qred(ahr) + bhhr);
            float z = sigm_f(gxz + qred(ahz) + bhhz);
            float n = tanh_f(gxn + r * (qred(ahn) + bhhn));
            hreg = (1.f - z) * n + z * hreg;
            if (ks == 0) h0Buf[IP * 80 + caddr] = hreg;
            // rotate gx pipeline (gx[i+1] -> current)
            gxr = qred(axr) + bihr;
            gxz = qred(axz) + bihz;
            gxn = qred(axn) + bihn;
        } else if (i >= 1) {
            // L1 step t=i-1: inputs h0[i-1] (slot IO), h1[i-2] (slot IP)
            const float4* ap = (const float4*)(h0Buf + IO * 80 + ks * 20);
            const float4* bp = (const float4*)(h1Buf + IP * 80 + ks * 20);
            float4 aq[4], bq[4];
            #pragma unroll
            for (int q = 0; q < 4; ++q) aq[q] = ap[q];
            #pragma unroll
            for (int q = 0; q < 4; ++q) bq[q] = bp[q];

            float ar = 0.f, az = 0.f, anx = 0.f, anh = 0.f;
            #pragma unroll
            for (int q = 0; q < 4; ++q) {
                const float4 a = aq[q];
                ar  = fmaf(wxr[4*q+0], a.x, ar);  ar  = fmaf(wxr[4*q+1], a.y, ar);
                ar  = fmaf(wxr[4*q+2], a.z, ar);  ar  = fmaf(wxr[4*q+3], a.w, ar);
                az  = fmaf(wxz[4*q+0], a.x, az);  az  = fmaf(wxz[4*q+1], a.y, az);
                az  = fmaf(wxz[4*q+2], a.z, az);  az  = fmaf(wxz[4*q+3], a.w, az);
                anx = fmaf(wxn[4*q+0], a.x, anx); anx = fmaf(wxn[4*q+1], a.y, anx);
                anx = fmaf(wxn[4*q+2], a.z, anx); anx = fmaf(wxn[4*q+3], a.w, anx);
            }
            #pragma unroll
            for (int q = 0; q < 4; ++q) {
                const float4 a = bq[q];
                ar  = fmaf(whr[4*q+0], a.x, ar);  ar  = fmaf(whr[4*q+1], a.y, ar);
                ar  = fmaf(whr[4*q+2], a.z, ar);  ar  = fmaf(whr[4*q+3], a.w, ar);
                az  = fmaf(whz[4*q+0], a.x, az);  az  = fmaf(whz[4*q+1], a.y, az);
                az  = fmaf(whz[4*q+2], a.z, az);  az  = fmaf(whz[4*q+3], a.w, az);
                anh = fmaf(whn[4*q+0], a.x, anh); anh = fmaf(whn[4*q+1], a.y, anh);
                anh = fmaf(whn[4*q+2], a.z, anh); anh = fmaf(whn[4*q+3], a.w, anh);
            }
            float r = sigm_f(qred(ar) + bihr);
            float z = sigm_f(qred(az) + bihz);
            float n = tanh_f(qred(anx) + bihn + r * (qred(anh) + bhhn));
            hreg = (1.f - z) * n + z * hreg;
            if (ks == 0) h1Buf[IO * 80 + caddr] = hreg;
        }

        barrier_lds();
    };

    for (int ii = 0; ii < T_STEPS / 2; ++ii) {
        step(2 * ii,     IC<0>{});
        step(2 * ii + 1, IC<1>{});
    }

    // ---- epilogue i = T_STEPS (even): L1 processes step T-1 ----
    if (isL1) {
        const float4* ap = (const float4*)(h0Buf + 80 + ks * 20);   // h0[T-1]
        const float4* bp = (const float4*)(h1Buf +  0 + ks * 20);   // h1[T-2]
        float4 aq[4], bq[4];
        #pragma unroll
        for (int q = 0; q < 4; ++q) aq[q] = ap[q];
        #pragma unroll
        for (int q = 0; q < 4; ++q) bq[q] = bp[q];
        float ar = 0.f, az = 0.f, anx = 0.f, anh = 0.f;
        #pragma unroll
        for (int q = 0; q < 4; ++q) {
            const float4 a = aq[q];
            ar  = fmaf(wxr[4*q+0], a.x, ar);  ar  = fmaf(wxr[4*q+1], a.y, ar);
            ar  = fmaf(wxr[4*q+2], a.z, ar);  ar  = fmaf(wxr[4*q+3], a.w, ar);
            az  = fmaf(wxz[4*q+0], a.x, az);  az  = fmaf(wxz[4*q+1], a.y, az);
            az  = fmaf(wxz[4*q+2], a.z, az);  az  = fmaf(wxz[4*q+3], a.w, az);
            anx = fmaf(wxn[4*q+0], a.x, anx); anx = fmaf(wxn[4*q+1], a.y, anx);
            anx = fmaf(wxn[4*q+2], a.z, anx); anx = fmaf(wxn[4*q+3], a.w, anx);
        }
        #pragma unroll
        for (int q = 0; q < 4; ++q) {
            const float4 a = bq[q];
            ar  = fmaf(whr[4*q+0], a.x, ar);  ar  = fmaf(whr[4*q+1], a.y, ar);
            ar  = fmaf(whr[4*q+2], a.z, ar);  ar  = fmaf(whr[4*q+3], a.w, ar);
            az  = fmaf(whz[4*q+0], a.x, az);  az  = fmaf(whz[4*q+1], a.y, az);
            az  = fmaf(whz[4*q+2], a.z, az);  az  = fmaf(whz[4*q+3], a.w, az);
            anh = fmaf(whn[4*q+0], a.x, anh); anh = fmaf(whn[4*q+1], a.y, anh);
            anh = fmaf(whn[4*q+2], a.z, anh); anh = fmaf(whn[4*q+3], a.w, anh);
        }
        float r = sigm_f(qred(ar) + bihr);
        float z = sigm_f(qred(az) + bihz);
        float n = tanh_f(qred(anx) + bihn + r * (qred(anh) + bhhn));
        hreg = (1.f - z) * n + z * hreg;
    }

    // ---- final states (lane's own hreg; no barrier needed) ----
    if (ks == 0) {
        if (!isL1) out_hidden[b * HDIM + jw] = hreg;                     // h0[T-1]
        else       out_hidden[BATCH * HDIM + b * HDIM + jw] = hreg;      // h1[T-1]
    }
}

// logits[b][o] = b_fc[o] + sum_j relu(h1T[b][j]) * W_fc[o][j]
__global__ void fc_kernel(const float* __restrict__ hidden,   // [2,B,H] region
                          const float* __restrict__ Wfc,      // [29,64]
                          const float* __restrict__ bfc,      // [29]
                          float* __restrict__ logits)         // [B,29]
{
    const int b = blockIdx.x;
    const int o = threadIdx.x;
    if (o < 29) {
        const float* hb = hidden + BATCH * HDIM + b * HDIM;   // h1T
        float acc = bfc[o];
        #pragma unroll
        for (int j = 0; j < HDIM; ++j)
            acc += fmaxf(hb[j], 0.f) * Wfc[o * HDIM + j];
        logits[b * 29 + o] = acc;
    }
}

extern "C" void kernel_launch(void* const* d_in, const int* in_sizes, int n_in,
                              void* d_out, int out_size, void* d_ws, size_t ws_size,
                              hipStream_t stream) {
    const float* x    = (const float*)d_in[0];
    const float* h    = (const float*)d_in[1];
    const float* Wih0 = (const float*)d_in[2];
    const float* Whh0 = (const float*)d_in[3];
    const float* bih0 = (const float*)d_in[4];
    const float* bhh0 = (const float*)d_in[5];
    const float* Wih1 = (const float*)d_in[6];
    const float* Whh1 = (const float*)d_in[7];
    const float* bih1 = (const float*)d_in[8];
    const float* bhh1 = (const float*)d_in[9];
    const float* Wfc  = (const float*)d_in[10];
    const float* bfc  = (const float*)d_in[11];

    float* out    = (float*)d_out;
    float* logits = out;                      // [256,29]
    float* hidden = out + BATCH * 29;         // [2,256,64]

    gru_fused<<<BATCH, 512, 0, stream>>>(
        x, h, Wih0, Whh0, bih0, bhh0, Wih1, Whh1, bih1, bhh1, hidden);

    fc_kernel<<<BATCH, 64, 0, stream>>>(hidden, Wfc, bfc, logits);
}

// Round 5
// 1245.870 us; speedup vs baseline: 1.9134x; 1.2211x over previous
//
#include <hip/hip_runtime.h>

#define T_STEPS 2000
#define BATCH   256
#define F_IN    80
#define HDIM    64

template<int N> struct IC { static constexpr int v = N; };

typedef _Float16 h2 __attribute__((ext_vector_type(2)));
typedef _Float16 h4 __attribute__((ext_vector_type(4)));
typedef _Float16 h8 __attribute__((ext_vector_type(8)));

union U8 { h8 v; h2 p[4]; };
union U4 { h4 v; h2 p[2]; };

// ---- fast transcendentals (fp32; logits threshold 1.77e-2) ----
__device__ __forceinline__ float sigm_f(float v) {
    float e = __expf(-v);
    return __builtin_amdgcn_rcpf(1.f + e);
}
__device__ __forceinline__ float tanh_f(float v) {
    v = fminf(fmaxf(v, -15.f), 15.f);
    float e = __expf(-2.f * v);
    return (1.f - e) * __builtin_amdgcn_rcpf(1.f + e);
}
// quad butterfly sum (lanes ks=0..3) via DPP quad_perm — VALU only.
__device__ __forceinline__ float qred(float v) {
    v += __int_as_float(__builtin_amdgcn_mov_dpp(__float_as_int(v), 0xB1, 0xF, 0xF, true));
    v += __int_as_float(__builtin_amdgcn_mov_dpp(__float_as_int(v), 0x4E, 0xF, 0xF, true));
    return v;
}
// LDS-only barrier: waits own LDS ops but leaves global loads in flight
// (avoids __syncthreads' vmcnt(0) drain of wave 7's x-prefetch).
__device__ __forceinline__ void barrier_lds() {
    __builtin_amdgcn_s_waitcnt(0xC07F);   // vmcnt=63, expcnt=7, lgkmcnt=0
    __builtin_amdgcn_s_barrier();
}
// v_dot2_f32_f16: 2 fp16 MACs, fp32 accumulate, one VALU instr.
__device__ __forceinline__ float fdot2(h2 a, h2 b, float c) {
    return __builtin_amdgcn_fdot2(a, b, c, false);
}
__device__ __forceinline__ h2 mk2(float a, float b) {
    h2 r; r.x = (_Float16)a; r.y = (_Float16)b; return r;
}

// One block per batch row. 512 threads = 8 waves, 2/SIMD.
//   waves 0..3 : layer 0. lane owns unit jw = 16*(w&3)+(lane>>2); K-chunk ks=lane&3.
//   waves 4..7 : layer 1, one step behind. wave 7 also stages x.
// Activations (x, h) live in LDS as fp16 (halves DS instrs + bytes); all state,
// accumulation (fdot2 -> fp32), gates, and the recurrent hreg stay fp32.
// L0's x-projection gx[i+1] is computed at iter i into registers (off-chain).
// ONE barrier per step; h buffers ping-pong by compile-time step parity.
__global__ __launch_bounds__(512, 2)
void gru_fused(const float* __restrict__ x,      // [B,T,F]
               const float* __restrict__ hin,    // [2,B,H]
               const float* __restrict__ Wih0,   // [192,80]
               const float* __restrict__ Whh0,   // [192,64]
               const float* __restrict__ bih0, const float* __restrict__ bhh0,
               const float* __restrict__ Wih1,   // [192,64]
               const float* __restrict__ Whh1,   // [192,64]
               const float* __restrict__ bih1, const float* __restrict__ bhh1,
               float* __restrict__ out_hidden)   // [2,B,H] region of d_out
{
    const int b    = blockIdx.x;
    const int tid  = threadIdx.x;
    const int lane = tid & 63;
    const int w    = tid >> 6;                  // 0..7
    const bool isL1 = (w >= 4);
    const int ks   = lane & 3;
    const int gg   = lane >> 2;
    const int jw   = ((w & 3) << 4) + gg;       // unit this lane owns

    // fp16 LDS. x chunks padded to 24 halves (48 B, keeps b128 16B-aligned and
    // <=2-way bank aliasing); h flat 64 halves (chunk = 16 halves = 2 b128).
    __shared__ __align__(16) _Float16 xsh[2][96];
    __shared__ __align__(16) _Float16 h0s[2][64];
    __shared__ __align__(16) _Float16 h1s[2][64];

    // ---- weights -> fp16 register pairs ----
    h2 wxr[10], wxz[10], wxn[10];   // L0: 20 x-elems; L1: 16 h0-elems (8 pairs)
    h2 whr[8],  whz[8],  whn[8];    // L0: Whh0 chunk; L1: Whh1 chunk
    float bihr, bihz, bihn, bhhr, bhhz, bhhn;
    if (!isL1) {
        const int c = ks * 20, c2 = ks * 16;
        const float* r0 = Wih0 + jw * F_IN + c;
        const float* r1 = Wih0 + (64 + jw) * F_IN + c;
        const float* r2 = Wih0 + (128 + jw) * F_IN + c;
        #pragma unroll
        for (int k = 0; k < 10; ++k) {
            wxr[k] = mk2(r0[2*k], r0[2*k+1]);
            wxz[k] = mk2(r1[2*k], r1[2*k+1]);
            wxn[k] = mk2(r2[2*k], r2[2*k+1]);
        }
        const float* s0 = Whh0 + jw * HDIM + c2;
        const float* s1 = Whh0 + (64 + jw) * HDIM + c2;
        const float* s2 = Whh0 + (128 + jw) * HDIM + c2;
        #pragma unroll
        for (int k = 0; k < 8; ++k) {
            whr[k] = mk2(s0[2*k], s0[2*k+1]);
            whz[k] = mk2(s1[2*k], s1[2*k+1]);
            whn[k] = mk2(s2[2*k], s2[2*k+1]);
        }
        bihr = bih0[jw];       bhhr = bhh0[jw];
        bihz = bih0[64 + jw];  bhhz = bhh0[64 + jw];
        bihn = bih0[128 + jw]; bhhn = bhh0[128 + jw];
    } else {
        const int c2 = ks * 16;
        const float* r0 = Wih1 + jw * HDIM + c2;
        const float* r1 = Wih1 + (64 + jw) * HDIM + c2;
        const float* r2 = Wih1 + (128 + jw) * HDIM + c2;
        const float* s0 = Whh1 + jw * HDIM + c2;
        const float* s1 = Whh1 + (64 + jw) * HDIM + c2;
        const float* s2 = Whh1 + (128 + jw) * HDIM + c2;
        #pragma unroll
        for (int k = 0; k < 8; ++k) {
            wxr[k] = mk2(r0[2*k], r0[2*k+1]);
            wxz[k] = mk2(r1[2*k], r1[2*k+1]);
            wxn[k] = mk2(r2[2*k], r2[2*k+1]);
            whr[k] = mk2(s0[2*k], s0[2*k+1]);
            whz[k] = mk2(s1[2*k], s1[2*k+1]);
            whn[k] = mk2(s2[2*k], s2[2*k+1]);
        }
        wxr[8] = mk2(0.f, 0.f); wxr[9] = mk2(0.f, 0.f);
        wxz[8] = mk2(0.f, 0.f); wxz[9] = mk2(0.f, 0.f);
        wxn[8] = mk2(0.f, 0.f); wxn[9] = mk2(0.f, 0.f);
        bihr = bih1[jw] + bhh1[jw];              // r: merged bias
        bihz = bih1[64 + jw] + bhh1[64 + jw];    // z: merged bias
        bihn = bih1[128 + jw];                   // n: x-side bias
        bhhn = bhh1[128 + jw];                   // n: h-side bias
        bhhr = 0.f; bhhz = 0.f;
    }

    // ---- state init ----
    float hreg = isL1 ? hin[BATCH * HDIM + b * HDIM + jw]
                      : hin[b * HDIM + jw];
    if (w == 0) {                                // slot 1 = parity of "step -1"
        h0s[1][lane] = (_Float16)hin[b * HDIM + lane];
        h1s[1][lane] = (_Float16)hin[BATCH * HDIM + b * HDIM + lane];
    }
    const float* xrow = x + (size_t)b * T_STEPS * F_IN;
    const int xe = 2 * lane;                     // element pair this lane stages
    const int xc = xe / 20, xpp = xe % 20;       // chunk / pos (pairs never straddle)
    float2 xa = make_float2(0.f, 0.f), xb = make_float2(0.f, 0.f);
    if (w == 7 && lane < 40) {                   // stage x0,x1; prefetch x2,x3
        float2 v0 = ((const float2*)(xrow + 0 * F_IN))[lane];
        float2 v1 = ((const float2*)(xrow + 1 * F_IN))[lane];
        *(h2*)(&xsh[0][xc * 24 + xpp]) = mk2(v0.x, v0.y);
        *(h2*)(&xsh[1][xc * 24 + xpp]) = mk2(v1.x, v1.y);
        xa = ((const float2*)(xrow + 2 * F_IN))[lane];
        xb = ((const float2*)(xrow + 3 * F_IN))[lane];
    }
    __syncthreads();   // prologue only

    // gx[0] from x slot 0 (registers; includes bih)
    float gxr = 0.f, gxz = 0.f, gxn = 0.f;
    if (!isL1) {
        U8 x0, x1; U4 x2;
        x0.v = ((const h8*)(&xsh[0][ks * 24]))[0];
        x1.v = ((const h8*)(&xsh[0][ks * 24]))[1];
        x2.v = *(const h4*)(&xsh[0][ks * 24 + 16]);
        float ar = 0.f, az = 0.f, an = 0.f;
        #pragma unroll
        for (int q = 0; q < 4; ++q) {
            ar = fdot2(wxr[q], x0.p[q], ar);
            az = fdot2(wxz[q], x0.p[q], az);
            an = fdot2(wxn[q], x0.p[q], an);
        }
        #pragma unroll
        for (int q = 0; q < 4; ++q) {
            ar = fdot2(wxr[4 + q], x1.p[q], ar);
            az = fdot2(wxz[4 + q], x1.p[q], az);
            an = fdot2(wxn[4 + q], x1.p[q], an);
        }
        #pragma unroll
        for (int q = 0; q < 2; ++q) {
            ar = fdot2(wxr[8 + q], x2.p[q], ar);
            az = fdot2(wxz[8 + q], x2.p[q], az);
            an = fdot2(wxn[8 + q], x2.p[q], an);
        }
        gxr = qred(ar) + bihr; gxz = qred(az) + bihz; gxn = qred(an) + bihn;
    }

    auto step = [&](int i, auto ipc) {
        constexpr int IP = decltype(ipc)::v;   // i&1
        constexpr int IO = IP ^ 1;             // (i-1)&1 == (i+1)&1

        // ---- x staging (wave 7): write x[i+2] -> slot IP; prefetch x[i+4] ----
        if (w == 7 && lane < 40) {
            float2 v = (IP == 0) ? xa : xb;
            *(h2*)(&xsh[IP][xc * 24 + xpp]) = mk2(v.x, v.y);
            if (i <= T_STEPS - 5) {
                float2 nv = ((const float2*)(xrow + (size_t)(i + 4) * F_IN))[lane];
                if (IP == 0) xa = nv; else xb = nv;
            }
        }

        if (!isL1) {
            // batched fp16 reads: h0[i-1] (2 b128) + x[i+1] (2 b128 + b64)
            U8 ha, hb;
            ha.v = ((const h8*)(&h0s[IO][ks * 16]))[0];
            hb.v = ((const h8*)(&h0s[IO][ks * 16]))[1];
            U8 x0, x1; U4 x2;
            x0.v = ((const h8*)(&xsh[IO][ks * 24]))[0];
            x1.v = ((const h8*)(&xsh[IO][ks * 24]))[1];
            x2.v = *(const h4*)(&xsh[IO][ks * 24 + 16]);

            // on-chain: gh = Whh0 . h0[i-1]
            float ahr = 0.f, ahz = 0.f, ahn = 0.f;
            #pragma unroll
            for (int q = 0; q < 4; ++q) {
                ahr = fdot2(whr[q], ha.p[q], ahr);
                ahz = fdot2(whz[q], ha.p[q], ahz);
                ahn = fdot2(whn[q], ha.p[q], ahn);
            }
            #pragma unroll
            for (int q = 0; q < 4; ++q) {
                ahr = fdot2(whr[4 + q], hb.p[q], ahr);
                ahz = fdot2(whz[4 + q], hb.p[q], ahz);
                ahn = fdot2(whn[4 + q], hb.p[q], ahn);
            }
            // gates + update for step i (gx[i] already in registers)
            float r = sigm_f(gxr + qred(ahr) + bhhr);
            float z = sigm_f(gxz + qred(ahz) + bhhz);
            float n = tanh_f(gxn + r * (qred(ahn) + bhhn));
            hreg = (1.f - z) * n + z * hreg;
            if (ks == 0) h0s[IP][jw] = (_Float16)hreg;

            // off-chain: gx[i+1] = Wih0 . x[i+1]
            float axr = 0.f, axz = 0.f, axn = 0.f;
            #pragma unroll
            for (int q = 0; q < 4; ++q) {
                axr = fdot2(wxr[q], x0.p[q], axr);
                axz = fdot2(wxz[q], x0.p[q], axz);
                axn = fdot2(wxn[q], x0.p[q], axn);
            }
            #pragma unroll
            for (int q = 0; q < 4; ++q) {
                axr = fdot2(wxr[4 + q], x1.p[q], axr);
                axz = fdot2(wxz[4 + q], x1.p[q], axz);
                axn = fdot2(wxn[4 + q], x1.p[q], axn);
            }
            #pragma unroll
            for (int q = 0; q < 2; ++q) {
                axr = fdot2(wxr[8 + q], x2.p[q], axr);
                axz = fdot2(wxz[8 + q], x2.p[q], axz);
                axn = fdot2(wxn[8 + q], x2.p[q], axn);
            }
            gxr = qred(axr) + bihr;
            gxz = qred(axz) + bihz;
            gxn = qred(axn) + bihn;
        } else if (i >= 1) {
            // L1 step t=i-1: inputs h0[i-1] (slot IO), h1[i-2] (slot IP)
            U8 aa, ab, ba, bb;
            aa.v = ((const h8*)(&h0s[IO][ks * 16]))[0];
            ab.v = ((const h8*)(&h0s[IO][ks * 16]))[1];
            ba.v = ((const h8*)(&h1s[IP][ks * 16]))[0];
            bb.v = ((const h8*)(&h1s[IP][ks * 16]))[1];
            float ar = 0.f, az = 0.f, anx = 0.f, anh = 0.f;
            #pragma unroll
            for (int q = 0; q < 4; ++q) {
                ar  = fdot2(wxr[q], aa.p[q], ar);
                az  = fdot2(wxz[q], aa.p[q], az);
                anx = fdot2(wxn[q], aa.p[q], anx);
            }
            #pragma unroll
            for (int q = 0; q < 4; ++q) {
                ar  = fdot2(wxr[4 + q], ab.p[q], ar);
                az  = fdot2(wxz[4 + q], ab.p[q], az);
                anx = fdot2(wxn[4 + q], ab.p[q], anx);
            }
            #pragma unroll
            for (int q = 0; q < 4; ++q) {
                ar  = fdot2(whr[q], ba.p[q], ar);
                az  = fdot2(whz[q], ba.p[q], az);
                anh = fdot2(whn[q], ba.p[q], anh);
            }
            #pragma unroll
            for (int q = 0; q < 4; ++q) {
                ar  = fdot2(whr[4 + q], bb.p[q], ar);
                az  = fdot2(whz[4 + q], bb.p[q], az);
                anh = fdot2(whn[4 + q], bb.p[q], anh);
            }
            float r = sigm_f(qred(ar) + bihr);
            float z = sigm_f(qred(az) + bihz);
            float n = tanh_f(qred(anx) + bihn + r * (qred(anh) + bhhn));
            hreg = (1.f - z) * n + z * hreg;
            if (ks == 0) h1s[IO][jw] = (_Float16)hreg;
        }

        barrier_lds();
    };

    for (int ii = 0; ii < T_STEPS / 2; ++ii) {
        step(2 * ii,     IC<0>{});
        step(2 * ii + 1, IC<1>{});
    }

    // ---- epilogue i = T_STEPS (even, IP=0, IO=1): L1 processes step T-1 ----
    if (isL1) {
        U8 aa, ab, ba, bb;
        aa.v = ((const h8*)(&h0s[1][ks * 16]))[0];   // h0[T-1]
        ab.v = ((const h8*)(&h0s[1][ks * 16]))[1];
        ba.v = ((const h8*)(&h1s[0][ks * 16]))[0];   // h1[T-2]
        bb.v = ((const h8*)(&h1s[0][ks * 16]))[1];
        float ar = 0.f, az = 0.f, anx = 0.f, anh = 0.f;
        #pragma unroll
        for (int q = 0; q < 4; ++q) {
            ar  = fdot2(wxr[q], aa.p[q], ar);
            az  = fdot2(wxz[q], aa.p[q], az);
            anx = fdot2(wxn[q], aa.p[q], anx);
        }
        #pragma unroll
        for (int q = 0; q < 4; ++q) {
            ar  = fdot2(wxr[4 + q], ab.p[q], ar);
            az  = fdot2(wxz[4 + q], ab.p[q], az);
            anx = fdot2(wxn[4 + q], ab.p[q], anx);
        }
        #pragma unroll
        for (int q = 0; q < 4; ++q) {
            ar  = fdot2(whr[q], ba.p[q], ar);
            az  = fdot2(whz[q], ba.p[q], az);
            anh = fdot2(whn[q], ba.p[q], anh);
        }
        #pragma unroll
        for (int q = 0; q < 4; ++q) {
            ar  = fdot2(whr[4 + q], bb.p[q], ar);
            az  = fdot2(whz[4 + q], bb.p[q], az);
            anh = fdot2(whn[4 + q], bb.p[q], anh);
        }
        float r = sigm_f(qred(ar) + bihr);
        float z = sigm_f(qred(az) + bihz);
        float n = tanh_f(qred(anx) + bihn + r * (qred(anh) + bhhn));
        hreg = (1.f - z) * n + z * hreg;
    }

    // ---- final states (lane's own fp32 hreg) ----
    if (ks == 0) {
        if (!isL1) out_hidden[b * HDIM + jw] = hreg;                 // h0[T-1]
        else       out_hidden[BATCH * HDIM + b * HDIM + jw] = hreg;  // h1[T-1]
    }
}

// logits[b][o] = b_fc[o] + sum_j relu(h1T[b][j]) * W_fc[o][j]
__global__ void fc_kernel(const float* __restrict__ hidden,   // [2,B,H] region
                          const float* __restrict__ Wfc,      // [29,64]
                          const float* __restrict__ bfc,      // [29]
                          float* __restrict__ logits)         // [B,29]
{
    const int b = blockIdx.x;
    const int o = threadIdx.x;
    if (o < 29) {
        const float* hb = hidden + BATCH * HDIM + b * HDIM;   // h1T
        float acc = bfc[o];
        #pragma unroll
        for (int j = 0; j < HDIM; ++j)
            acc += fmaxf(hb[j], 0.f) * Wfc[o * HDIM + j];
        logits[b * 29 + o] = acc;
    }
}

extern "C" void kernel_launch(void* const* d_in, const int* in_sizes, int n_in,
                              void* d_out, int out_size, void* d_ws, size_t ws_size,
                              hipStream_t stream) {
    const float* x    = (const float*)d_in[0];
    const float* h    = (const float*)d_in[1];
    const float* Wih0 = (const float*)d_in[2];
    const float* Whh0 = (const float*)d_in[3];
    const float* bih0 = (const float*)d_in[4];
    const float* bhh0 = (const float*)d_in[5];
    const float* Wih1 = (const float*)d_in[6];
    const float* Whh1 = (const float*)d_in[7];
    const float* bih1 = (const float*)d_in[8];
    const float* bhh1 = (const float*)d_in[9];
    const float* Wfc  = (const float*)d_in[10];
    const float* bfc  = (const float*)d_in[11];

    float* out    = (float*)d_out;
    float* logits = out;                      // [256,29]
    float* hidden = out + BATCH * 29;         // [2,256,64]

    gru_fused<<<BATCH, 512, 0, stream>>>(
        x, h, Wih0, Whh0, bih0, bhh0, Wih1, Whh1, bih1, bhh1, hidden);

    fc_kernel<<<BATCH, 64, 0, stream>>>(hidden, Wfc, bfc, logits);
}